// Round 11
// baseline (2514.088 us; speedup 1.0000x reference)
//
#include <hip/hip_runtime.h>
#include <hip/hip_bf16.h>

#define NN 40000
#define EE 640000
#define CCH 128
#define GG 64

typedef __attribute__((ext_vector_type(8))) short short8;
typedef __attribute__((ext_vector_type(4))) float f32x4;

__device__ __forceinline__ float lrelu01(float v){ return v > 0.f ? v : 0.01f*v; }
__device__ __forceinline__ float sigm(float v){ return 1.f/(1.f + __expf(-v)); }
__device__ __forceinline__ float tanh_f(float v){
  v = fminf(fmaxf(v, -15.f), 15.f);
  const float t = __expf(2.f*v);
  return (t - 1.f)/(t + 1.f);
}
__device__ __forceinline__ unsigned short f2bf(float f){
  union { float f; unsigned int u; } v; v.f = f;
  const unsigned int r = v.u + 0x7FFFu + ((v.u >> 16) & 1u);
  return (unsigned short)(r >> 16);
}
__device__ __forceinline__ float bf2f(unsigned short h){
  union { unsigned int u; float f; } v; v.u = ((unsigned int)h) << 16;
  return v.f;
}
// 2-term split: x = hi + lo (~2^-17 rel err; error floor is agg ordering, r4/r5 evidence)
__device__ __forceinline__ void split2v(const float4 a, const float4 b, short8& hi, short8& lo){
  const float v[8] = {a.x,a.y,a.z,a.w,b.x,b.y,b.z,b.w};
#pragma unroll
  for (int i=0;i<8;++i){
    const unsigned short h = f2bf(v[i]);
    hi[i] = (short)h;
    lo[i] = (short)f2bf(v[i] - bf2f(h));
  }
}
// dual-dtype loads: flags[0]=floats are f32, flags[1]=ints are i64
__device__ __forceinline__ float LDF(const void* p, int f32, size_t i){
  return f32 ? ((const float*)p)[i] : bf2f(((const unsigned short*)p)[i]);
}
__device__ __forceinline__ int LDI(const void* p, int i64, size_t i){
  return i64 ? (int)((const long long*)p)[i] : ((const int*)p)[i];
}

// ---------------- dtype detection (device-side, graph-safe) ----------------
__global__ __launch_bounds__(256) void k_detect(const unsigned short* __restrict__ xh,
                                                const unsigned int* __restrict__ ei,
                                                int* __restrict__ flags){
  __shared__ int s1[256], s2[256];
  const int t = threadIdx.x;
  int c1 = 0, c2 = 0;
  for (int i=0;i<8;++i){
    const unsigned short w = xh[t*8 + i];
    const int e = (w >> 7) & 0xFF;
    if (e < 100 || e > 140) c1++;
    const unsigned int o = ei[(t*8 + i)*2 + 1];
    if (o) c2++;
  }
  s1[t]=c1; s2[t]=c2; __syncthreads();
  for (int off=128; off; off>>=1){ if (t<off){ s1[t]+=s1[t+off]; s2[t]+=s2[t+off]; } __syncthreads(); }
  if (t==0){
    flags[0] = (s1[0] > 64) ? 1 : 0;
    flags[1] = (s2[0] < 16) ? 1 : 0;
  }
}

// ---------------- CSR build ----------------
__global__ __launch_bounds__(256) void k_hist(const void* __restrict__ eidx, const int* __restrict__ flags,
                                              int* __restrict__ deg){
  const int e = blockIdx.x*256 + threadIdx.x;
  if (e >= EE) return;
  atomicAdd(&deg[LDI(eidx, flags[1], (size_t)EE + e)], 1);
}

__global__ __launch_bounds__(256) void k_scan1(const int* __restrict__ deg, int* __restrict__ bsum){
  __shared__ int s[256];
  const int t = threadIdx.x;
  const int i = blockIdx.x*256 + t;
  s[t] = (i < NN) ? deg[i] : 0;
  __syncthreads();
  for (int off=128; off; off>>=1){ if (t<off) s[t]+=s[t+off]; __syncthreads(); }
  if (t==0) bsum[blockIdx.x] = s[0];
}

__global__ __launch_bounds__(256) void k_scan2(const int* __restrict__ bsum, int* __restrict__ boff,
                                               int* __restrict__ roff){
  __shared__ int s[256];
  const int t = threadIdx.x;
  const int v = (t < 157) ? bsum[t] : 0;
  s[t] = v; __syncthreads();
  for (int off=1; off<256; off<<=1){
    const int u = (t>=off) ? s[t-off] : 0;
    __syncthreads(); s[t] += u; __syncthreads();
  }
  if (t < 157) boff[t] = s[t] - v;   // exclusive
  if (t == 0) roff[NN] = EE;
}

__global__ __launch_bounds__(256) void k_scan3(const int* __restrict__ deg, const int* __restrict__ boff,
                                               int* __restrict__ roff, int* __restrict__ pos){
  __shared__ int s[256];
  const int t = threadIdx.x;
  const int i = blockIdx.x*256 + t;
  const int v = (i < NN) ? deg[i] : 0;
  s[t] = v; __syncthreads();
  for (int off=1; off<256; off<<=1){
    const int u = (t>=off) ? s[t-off] : 0;
    __syncthreads(); s[t] += u; __syncthreads();
  }
  if (i < NN){
    const int ex = boff[blockIdx.x] + s[t] - v;
    roff[i] = ex; pos[i] = ex;
  }
}

__global__ __launch_bounds__(256) void k_scatter(const void* __restrict__ eidx, const void* __restrict__ ew,
                                                 const int* __restrict__ flags,
                                                 int* __restrict__ pos, int* __restrict__ es, float* __restrict__ ewt){
  const int e = blockIdx.x*256 + threadIdx.x;
  if (e >= EE) return;
  const int i64 = flags[1];
  const int d = LDI(eidx, i64, (size_t)EE + e);
  const int p = atomicAdd(&pos[d], 1);
  es[p] = LDI(eidx, i64, e);
  ewt[p] = LDF(ew, flags[0], e);
}

// ---------------- converts ----------------
__global__ __launch_bounds__(256) void k_x2f(const void* __restrict__ xin, const int* __restrict__ flags,
                                             float* __restrict__ xf){
  const int i = blockIdx.x*256 + threadIdx.x;
  if (i < NN*CCH) xf[i] = LDF(xin, flags[0], i);
}

__global__ __launch_bounds__(256) void k_batcvt(const void* __restrict__ batch, const int* __restrict__ flags,
                                                int* __restrict__ bat32){
  const int i = blockIdx.x*256 + threadIdx.x;
  if (i < NN) bat32[i] = LDI(batch, flags[1], i);
}

__global__ __launch_bounds__(256) void k_wcvt_bf(const void* __restrict__ w, const int* __restrict__ flags,
                                                 const size_t off, unsigned short* __restrict__ o, const int n){
  const int i = blockIdx.x*256 + threadIdx.x;
  if (i < n) o[i] = f2bf(LDF(w, flags[0], off + i));
}

// ---------------- Wc[t] = convW[t] @ wih[L(t)]^T, stored Bt-layout [t][col][k], hi/lo split ----
// grid 180: t = bx/12 (15 steps), tile = bx%12 (32 cols each of 384)
__global__ __launch_bounds__(256) void k_mkWc(const void* __restrict__ cw, const void* __restrict__ wih,
                                              const int* __restrict__ flags,
                                              unsigned short* __restrict__ wcH, unsigned short* __restrict__ wcL){
  __shared__ unsigned short sW[128*128];   // [k][j], 32 KB
  __shared__ unsigned short sI[32*136];    // [colLocal][j] padded, 8.5 KB
  const int tid = threadIdx.x;
  const int t = blockIdx.x / 12, tile = blockIdx.x % 12;
  int L=0, s=t;
  if (t>=14){L=4;s=t-14;} else if(t>=12){L=3;s=t-12;} else if(t>=9){L=2;s=t-9;} else if(t>=5){L=1;s=t-5;}
  const int f32 = flags[0];
  const size_t woff = (size_t)(L*5+s)*16384;
  const size_t ioff = (size_t)L*49152 + (size_t)tile*32*128;
  for (int u=tid; u<16384; u+=256) sW[u] = f2bf(LDF(cw, f32, woff + u));
  for (int u=tid; u<4096; u+=256){
    const int r = u>>7, jj = u&127;
    sI[r*136 + jj] = f2bf(LDF(wih, f32, ioff + r*128 + jj));
  }
  __syncthreads();
  const int cl = tid & 31;
  const int kb = (tid>>5)*16;
  for (int k=kb; k<kb+16; ++k){
    float acc = 0.f;
#pragma unroll 4
    for (int j8=0; j8<16; ++j8){
      const short8 a = *(const short8*)(sW + k*128 + j8*8);
      const short8 b = *(const short8*)(sI + cl*136 + j8*8);
#pragma unroll
      for (int q=0;q<8;++q) acc += bf2f((unsigned short)a[q]) * bf2f((unsigned short)b[q]);
    }
    const unsigned short h = f2bf(acc);
    const unsigned short l = f2bf(acc - bf2f(h));
    const size_t oidx = (size_t)t*49152 + (size_t)(tile*32 + cl)*128 + k;
    wcH[oidx] = h; wcL[oidx] = l;
  }
}

// ---------------- xg[dst] = sum ew * x[src]  (FROZEN body — summation order fixed since r4) ----
__global__ __launch_bounds__(256) void k_agg(const float* __restrict__ m, const int* __restrict__ roff,
                                             const int* __restrict__ es, const float* __restrict__ ewt,
                                             float* __restrict__ agg, const int useW){
  const int node = (blockIdx.x*256 + threadIdx.x) >> 6;
  if (node >= NN) return;
  const int lane = threadIdx.x & 63;
  const int h = lane >> 5, j = lane & 31;
  const int beg = roff[node], end = roff[node+1];
  float ax=0.f, ay=0.f, az=0.f, aw=0.f;
  int e = beg + h;
  for (; e + 2 < end; e += 4){
    const int s0 = es[e], s1 = es[e+2];
    const float w0 = useW ? ewt[e] : 1.f;
    const float w1 = useW ? ewt[e+2] : 1.f;
    const float4 v0 = *(const float4*)(m + (size_t)s0*CCH + j*4);
    const float4 v1 = *(const float4*)(m + (size_t)s1*CCH + j*4);
    ax += w0*v0.x + w1*v1.x; ay += w0*v0.y + w1*v1.y;
    az += w0*v0.z + w1*v1.z; aw += w0*v0.w + w1*v1.w;
  }
  if (e < end){
    const int s0 = es[e];
    const float w0 = useW ? ewt[e] : 1.f;
    const float4 v0 = *(const float4*)(m + (size_t)s0*CCH + j*4);
    ax += w0*v0.x; ay += w0*v0.y; az += w0*v0.z; aw += w0*v0.w;
  }
  ax += __shfl_xor(ax, 32); ay += __shfl_xor(ay, 32);
  az += __shfl_xor(az, 32); aw += __shfl_xor(aw, 32);
  if (h == 0){
    float4 ov; ov.x=ax; ov.y=ay; ov.z=az; ov.w=aw;
    *(float4*)(agg + (size_t)node*CCH + j*4) = ov;
  }
}

// ---------------- fused conv+GRU via MFMA: xf = GRU(xg@Wc, xf) in place ----------------
// 2 TILES PER WAVE: 256 thr (4 waves) x 32 nodes = 128 nodes/block, grid 313.
// r8's cycle model: 36 ds_read_b128 (432cy) fed only 60 MFMA (288cy) -> LDS-read-bound.
// Now the same 36 reads feed 120 MFMA (576cy) -> MFMA-issue-bound. ~200 VGPR -> 2 blocks/CU,
// so the 57 CUs holding 2 blocks run them CONCURRENTLY (r8 ran them back-to-back).
// Per-element MFMA order unchanged -> absmax identical.
__global__ __launch_bounds__(256) void k_gru(const float* __restrict__ xg,
                                             float* __restrict__ xf,
                                             const unsigned short* __restrict__ wcH,  // [384][128]
                                             const unsigned short* __restrict__ wcL,  // [384][128]
                                             const unsigned short* __restrict__ whB,  // [384][128]
                                             const void* __restrict__ bih, const void* __restrict__ bhh,
                                             const size_t boff, const int* __restrict__ flags){
  __shared__ unsigned short s_w[9*16*128];   // 36864 B
  const int tid = threadIdx.x;
  const int wv = tid >> 6;
  const int lane = tid & 63;
  const int quad = lane >> 4;
  const int ln = lane & 15;
  const int m0 = blockIdx.x*128 + wv*32;     // wave: 32 nodes (two 16-row tiles)
  const int f32 = flags[0];
  short8 fah[2][4], fal[2][4], fxh[2][4], fxl[2][4];
#pragma unroll
  for (int t=0;t<2;++t){
    int arow = m0 + t*16 + ln; if (arow >= NN) arow = NN-1;
    const float* pa = xg + (size_t)arow*CCH + quad*8;
    const float* px = xf + (size_t)arow*CCH + quad*8;
#pragma unroll
    for (int kk=0;kk<4;++kk){
      split2v(*(const float4*)(pa+kk*32), *(const float4*)(pa+kk*32+4), fah[t][kk], fal[t][kk]);
      split2v(*(const float4*)(px+kk*32), *(const float4*)(px+kk*32+4), fxh[t][kk], fxl[t][kk]);
    }
  }
#pragma unroll 1
  for (int ct=0; ct<8; ++ct){
    __syncthreads();   // previous iteration's LDS reads complete
    // stage: chunk = mat*3+gate; mat 0=wcH 1=wcL 2=whB; 16 cols x 16 parts each
    for (int u = tid; u < 2304; u += 256){
      const int chunk = u >> 8;
      const int rem = u & 255;
      const int c = rem >> 4, p = rem & 15;
      const int mat = chunk / 3, g = chunk - mat*3;
      const unsigned short* msrc = (mat==0) ? wcH : ((mat==1) ? wcL : whB);
      const unsigned short* src = msrc + ((size_t)(g*CCH + ct*16 + c)*CCH + p*8);
      *(short8*)(s_w + chunk*2048 + c*128 + ((p ^ c)*8)) = *(const short8*)src;
    }
    __syncthreads();
    f32x4 acci[2][3], acch[2][3];
#pragma unroll
    for (int t=0;t<2;++t)
#pragma unroll
      for (int g=0;g<3;++g){ acci[t][g] = (f32x4){0.f,0.f,0.f,0.f}; acch[t][g] = (f32x4){0.f,0.f,0.f,0.f}; }
#pragma unroll
    for (int kk=0;kk<4;++kk){
      const int sw = ((kk*4+quad) ^ ln)*8;
#pragma unroll
      for (int g=0;g<3;++g){
        const short8 bh_ = *(const short8*)(s_w + g*2048     + ln*128 + sw);
        const short8 bl_ = *(const short8*)(s_w + (3+g)*2048 + ln*128 + sw);
        const short8 bb_ = *(const short8*)(s_w + (6+g)*2048 + ln*128 + sw);
#pragma unroll
        for (int t=0;t<2;++t){
          acci[t][g] = __builtin_amdgcn_mfma_f32_16x16x32_bf16(fah[t][kk], bh_, acci[t][g], 0, 0, 0);
          acci[t][g] = __builtin_amdgcn_mfma_f32_16x16x32_bf16(fal[t][kk], bh_, acci[t][g], 0, 0, 0);
          acci[t][g] = __builtin_amdgcn_mfma_f32_16x16x32_bf16(fah[t][kk], bl_, acci[t][g], 0, 0, 0);
          acch[t][g] = __builtin_amdgcn_mfma_f32_16x16x32_bf16(fxh[t][kk], bb_, acch[t][g], 0, 0, 0);
          acch[t][g] = __builtin_amdgcn_mfma_f32_16x16x32_bf16(fxl[t][kk], bb_, acch[t][g], 0, 0, 0);
        }
      }
    }
    const int col = ct*16 + ln;
    float bi[3], bh[3];
#pragma unroll
    for (int g=0;g<3;++g){
      bi[g] = LDF(bih, f32, boff + g*CCH + col);
      bh[g] = LDF(bhh, f32, boff + g*CCH + col);
    }
#pragma unroll
    for (int t=0;t<2;++t)
#pragma unroll
      for (int r=0;r<4;++r){
        const int row = m0 + t*16 + quad*4 + r;
        if (row < NN){
          const size_t idx = (size_t)row*CCH + col;
          const float h = xf[idx];
          const float rr = sigm(acci[t][0][r] + acch[t][0][r] + bi[0] + bh[0]);
          const float zz = sigm(acci[t][1][r] + acch[t][1][r] + bi[1] + bh[1]);
          const float nv = tanh_f(acci[t][2][r] + bi[2] + rr*(acch[t][2][r] + bh[2]));
          xf[idx] = (1.f - zz)*nv + zz*h;
        }
      }
  }
}

// ---------------- GraphNorm ----------------
__global__ __launch_bounds__(256) void k_gn_stats(const float* __restrict__ x, float* __restrict__ accum, const int pre){
  const int tid = threadIdx.x;
  const int ch = tid & 127;
  const int half = tid >> 7;
  const int node0 = blockIdx.x * 128;
  float s = 0.f, s2 = 0.f;
  for (int r = half; r < 128; r += 2){
    const int n = node0 + r;
    if (n >= NN) break;
    float v = x[(size_t)n*CCH + ch];
    if (pre) v = lrelu01(v);
    s += v; s2 += v*v;
  }
  __shared__ float buf[256];
  buf[tid] = s; __syncthreads();
  if (tid < 128) atomicAdd(&accum[ch], buf[tid] + buf[tid+128]);
  __syncthreads();
  buf[tid] = s2; __syncthreads();
  if (tid < 128) atomicAdd(&accum[128+ch], buf[tid] + buf[tid+128]);
}

__global__ void k_gn_final(const float* __restrict__ accum, const void* __restrict__ gw,
                           const void* __restrict__ gb, const void* __restrict__ gms,
                           const size_t off, const int* __restrict__ flags, float* __restrict__ par){
  const int j = threadIdx.x;
  const int f32 = flags[0];
  const float inv = 1.f/(float)NN;
  const float mean = accum[j]*inv;
  const float m2 = accum[128+j]*inv;
  const float ms = LDF(gms, f32, off + j);
  const float var = m2 - 2.f*ms*mean*mean + ms*ms*mean*mean;
  const float sc = LDF(gw, f32, off + j) / sqrtf(var + 1e-5f);
  par[j] = sc;
  par[128+j] = LDF(gb, f32, off + j) - sc*ms*mean;
}

// mode 0: lrelu(a*x+c)   mode 1: a*lrelu(x)+c
__global__ __launch_bounds__(256) void k_gn_apply(float* __restrict__ xf, const float* __restrict__ par, const int mode){
  const int i = blockIdx.x*256 + threadIdx.x;
#pragma unroll
  for (int r=0;r<8;++r){
    const int idx = i + r*640000;
    float v = xf[idx];
    const int ch = idx & 127;
    if (mode == 1) v = lrelu01(v);
    v = par[ch]*v + par[128+ch];
    if (mode == 0) v = lrelu01(v);
    xf[idx] = v;
  }
}

// ---------------- final: lrelu + segment sum (batch sorted -> run-flush atomics) ----------------
__global__ __launch_bounds__(256) void k_final(const float* __restrict__ x, const int* __restrict__ bat,
                                               float* __restrict__ outf){
  const int t = threadIdx.x;
  const int ch = t & 127;
  const int half = t >> 7;
  const int n0 = blockIdx.x*32;
  int cur = -1; float acc = 0.f;
  for (int r = half; r < 32; r += 2){
    const int n = n0 + r;
    const int b = bat[n];
    if (b != cur){
      if (cur >= 0) atomicAdd(&outf[cur*CCH + ch], acc);
      cur = b; acc = 0.f;
    }
    acc += lrelu01(x[(size_t)n*CCH + ch]);
  }
  if (cur >= 0) atomicAdd(&outf[cur*CCH + ch], acc);
}

__global__ __launch_bounds__(256) void k_store(const float* __restrict__ outf, const int* __restrict__ flags, void* __restrict__ out){
  const int i = blockIdx.x*256 + threadIdx.x;
  if (i >= GG*CCH) return;
  if (flags[0]) ((float*)out)[i] = outf[i];
  else ((unsigned short*)out)[i] = f2bf(outf[i]);
}

extern "C" void kernel_launch(void* const* d_in, const int* in_sizes, int n_in,
                              void* d_out, int out_size, void* d_ws, size_t ws_size,
                              hipStream_t stream){
  const void* x_in = d_in[0];
  const void* ew   = d_in[1];
  const void* cw   = d_in[2];
  const void* wih  = d_in[3];
  const void* whh  = d_in[4];
  const void* bih  = d_in[5];
  const void* bhh  = d_in[6];
  const void* gnw  = d_in[7];
  const void* gnb  = d_in[8];
  const void* gnms = d_in[9];
  const void* eidx  = d_in[10];
  const void* batch = d_in[11];

  float* base = (float*)d_ws;
  size_t o = 0;
  float* xf     = base + o; o += (size_t)NN*CCH;   // fp32 state (in-place updated)
  float* xg     = base + o; o += (size_t)NN*CCH;   // gather output
  unsigned short* wcH = (unsigned short*)(base + o); o += 15*384*CCH/2;
  unsigned short* wcL = (unsigned short*)(base + o); o += 15*384*CCH/2;
  unsigned short* whB5= (unsigned short*)(base + o); o += 5*384*CCH/2;
  float* ewt    = base + o; o += EE;
  float* gnpar  = base + o; o += 256;
  int* flags    = (int*)(base + o); o += 2;
  int* bat32    = (int*)(base + o); o += NN;
  int* bsum     = (int*)(base + o); o += 160;
  int* boff2    = (int*)(base + o); o += 160;
  // ---- zero zone (one memset covers outf + gnacc + deg) ----
  float* outf   = base + o; o += GG*CCH;   // 8192
  float* gnacc  = base + o; o += 1024;     // 4 layers x 256
  int* deg      = (int*)(base + o); o += NN;
  // ---- end zero zone ----
  int* roff     = (int*)(base + o); o += NN+1;
  int* pos      = (int*)(base + o); o += NN;
  int* es       = (int*)(base + o); o += EE;

  hipMemsetAsync(outf, 0, (size_t)(GG*CCH + 1024 + NN)*4, stream);

  k_detect<<<1,256,0,stream>>>((const unsigned short*)x_in, (const unsigned int*)eidx, flags);
  k_hist<<<2500,256,0,stream>>>(eidx, flags, deg);
  k_scan1<<<157,256,0,stream>>>(deg, bsum);
  k_scan2<<<1,256,0,stream>>>(bsum, boff2, roff);
  k_scan3<<<157,256,0,stream>>>(deg, boff2, roff, pos);
  k_scatter<<<2500,256,0,stream>>>(eidx, ew, flags, pos, es, ewt);
  k_x2f<<<20000,256,0,stream>>>(x_in, flags, xf);
  k_batcvt<<<157,256,0,stream>>>(batch, flags, bat32);
  for (int L=0; L<5; ++L)
    k_wcvt_bf<<<192,256,0,stream>>>(whh, flags, (size_t)L*384*CCH, whB5 + (size_t)L*384*CCH, 384*CCH);
  k_mkWc<<<180,256,0,stream>>>(cw, wih, flags, wcH, wcL);

  const int steps[5] = {5,4,3,2,1};
  int t = 0;
  for (int L=0; L<5; ++L){
    for (int s=0; s<steps[L]; ++s){
      k_agg<<<10000,256,0,stream>>>(xf, roff, es, ewt, xg, (L<4) ? 1 : 0);
      k_gru<<<313,256,0,stream>>>(xg, xf,
                                  wcH + (size_t)t*384*CCH, wcL + (size_t)t*384*CCH,
                                  whB5 + (size_t)L*384*CCH, bih, bhh, (size_t)L*384, flags);
      t++;
    }
    if (L < 4){
      const int pre = (L==0) ? 0 : 1;
      k_gn_stats<<<313,256,0,stream>>>(xf, gnacc + L*256, pre);
      k_gn_final<<<1,128,0,stream>>>(gnacc + L*256, gnw, gnb, gnms, (size_t)L*CCH, flags, gnpar);
      k_gn_apply<<<2500,256,0,stream>>>(xf, gnpar, pre);
    }
  }
  k_final<<<1250,256,0,stream>>>(xf, bat32, outf);
  k_store<<<32,256,0,stream>>>(outf, flags, d_out);
}

// Round 12
// 1727.799 us; speedup vs baseline: 1.4551x; 1.4551x over previous
//
#include <hip/hip_runtime.h>
#include <hip/hip_bf16.h>

#define NN 40000
#define EE 640000
#define CCH 128
#define GG 64

typedef __attribute__((ext_vector_type(8))) short short8;
typedef __attribute__((ext_vector_type(4))) float f32x4;

__device__ __forceinline__ float lrelu01(float v){ return v > 0.f ? v : 0.01f*v; }
__device__ __forceinline__ float sigm(float v){ return 1.f/(1.f + __expf(-v)); }
__device__ __forceinline__ float tanh_f(float v){
  v = fminf(fmaxf(v, -15.f), 15.f);
  const float t = __expf(2.f*v);
  return (t - 1.f)/(t + 1.f);
}
__device__ __forceinline__ unsigned short f2bf(float f){
  union { float f; unsigned int u; } v; v.f = f;
  const unsigned int r = v.u + 0x7FFFu + ((v.u >> 16) & 1u);
  return (unsigned short)(r >> 16);
}
__device__ __forceinline__ float bf2f(unsigned short h){
  union { unsigned int u; float f; } v; v.u = ((unsigned int)h) << 16;
  return v.f;
}
// 2-term split: x = hi + lo (~2^-17 rel err; error floor is agg ordering, r4/r5 evidence)
__device__ __forceinline__ void split2v(const float4 a, const float4 b, short8& hi, short8& lo){
  const float v[8] = {a.x,a.y,a.z,a.w,b.x,b.y,b.z,b.w};
#pragma unroll
  for (int i=0;i<8;++i){
    const unsigned short h = f2bf(v[i]);
    hi[i] = (short)h;
    lo[i] = (short)f2bf(v[i] - bf2f(h));
  }
}
// dual-dtype loads: flags[0]=floats are f32, flags[1]=ints are i64
__device__ __forceinline__ float LDF(const void* p, int f32, size_t i){
  return f32 ? ((const float*)p)[i] : bf2f(((const unsigned short*)p)[i]);
}
__device__ __forceinline__ int LDI(const void* p, int i64, size_t i){
  return i64 ? (int)((const long long*)p)[i] : ((const int*)p)[i];
}

// ---------------- dtype detection (device-side, graph-safe) ----------------
__global__ __launch_bounds__(256) void k_detect(const unsigned short* __restrict__ xh,
                                                const unsigned int* __restrict__ ei,
                                                int* __restrict__ flags){
  __shared__ int s1[256], s2[256];
  const int t = threadIdx.x;
  int c1 = 0, c2 = 0;
  for (int i=0;i<8;++i){
    const unsigned short w = xh[t*8 + i];
    const int e = (w >> 7) & 0xFF;
    if (e < 100 || e > 140) c1++;
    const unsigned int o = ei[(t*8 + i)*2 + 1];
    if (o) c2++;
  }
  s1[t]=c1; s2[t]=c2; __syncthreads();
  for (int off=128; off; off>>=1){ if (t<off){ s1[t]+=s1[t+off]; s2[t]+=s2[t+off]; } __syncthreads(); }
  if (t==0){
    flags[0] = (s1[0] > 64) ? 1 : 0;
    flags[1] = (s2[0] < 16) ? 1 : 0;
  }
}

// ---------------- CSR build ----------------
__global__ __launch_bounds__(256) void k_hist(const void* __restrict__ eidx, const int* __restrict__ flags,
                                              int* __restrict__ deg){
  const int e = blockIdx.x*256 + threadIdx.x;
  if (e >= EE) return;
  atomicAdd(&deg[LDI(eidx, flags[1], (size_t)EE + e)], 1);
}

__global__ __launch_bounds__(256) void k_scan1(const int* __restrict__ deg, int* __restrict__ bsum){
  __shared__ int s[256];
  const int t = threadIdx.x;
  const int i = blockIdx.x*256 + t;
  s[t] = (i < NN) ? deg[i] : 0;
  __syncthreads();
  for (int off=128; off; off>>=1){ if (t<off) s[t]+=s[t+off]; __syncthreads(); }
  if (t==0) bsum[blockIdx.x] = s[0];
}

__global__ __launch_bounds__(256) void k_scan2(const int* __restrict__ bsum, int* __restrict__ boff,
                                               int* __restrict__ roff){
  __shared__ int s[256];
  const int t = threadIdx.x;
  const int v = (t < 157) ? bsum[t] : 0;
  s[t] = v; __syncthreads();
  for (int off=1; off<256; off<<=1){
    const int u = (t>=off) ? s[t-off] : 0;
    __syncthreads(); s[t] += u; __syncthreads();
  }
  if (t < 157) boff[t] = s[t] - v;   // exclusive
  if (t == 0) roff[NN] = EE;
}

__global__ __launch_bounds__(256) void k_scan3(const int* __restrict__ deg, const int* __restrict__ boff,
                                               int* __restrict__ roff, int* __restrict__ pos){
  __shared__ int s[256];
  const int t = threadIdx.x;
  const int i = blockIdx.x*256 + t;
  const int v = (i < NN) ? deg[i] : 0;
  s[t] = v; __syncthreads();
  for (int off=1; off<256; off<<=1){
    const int u = (t>=off) ? s[t-off] : 0;
    __syncthreads(); s[t] += u; __syncthreads();
  }
  if (i < NN){
    const int ex = boff[blockIdx.x] + s[t] - v;
    roff[i] = ex; pos[i] = ex;
  }
}

__global__ __launch_bounds__(256) void k_scatter(const void* __restrict__ eidx, const void* __restrict__ ew,
                                                 const int* __restrict__ flags,
                                                 int* __restrict__ pos, int* __restrict__ es, float* __restrict__ ewt){
  const int e = blockIdx.x*256 + threadIdx.x;
  if (e >= EE) return;
  const int i64 = flags[1];
  const int d = LDI(eidx, i64, (size_t)EE + e);
  const int p = atomicAdd(&pos[d], 1);
  es[p] = LDI(eidx, i64, e);
  ewt[p] = LDF(ew, flags[0], e);
}

// ---------------- converts ----------------
__global__ __launch_bounds__(256) void k_x2f(const void* __restrict__ xin, const int* __restrict__ flags,
                                             float* __restrict__ xf){
  const int i = blockIdx.x*256 + threadIdx.x;
  if (i < NN*CCH) xf[i] = LDF(xin, flags[0], i);
}

__global__ __launch_bounds__(256) void k_batcvt(const void* __restrict__ batch, const int* __restrict__ flags,
                                                int* __restrict__ bat32){
  const int i = blockIdx.x*256 + threadIdx.x;
  if (i < NN) bat32[i] = LDI(batch, flags[1], i);
}

__global__ __launch_bounds__(256) void k_wcvt_bf(const void* __restrict__ w, const int* __restrict__ flags,
                                                 const size_t off, unsigned short* __restrict__ o, const int n){
  const int i = blockIdx.x*256 + threadIdx.x;
  if (i < n) o[i] = f2bf(LDF(w, flags[0], off + i));
}

// ---------------- Wc[t] = convW[t] @ wih[L(t)]^T, stored Bt-layout [t][col][k], hi/lo split ----
// grid 180: t = bx/12 (15 steps), tile = bx%12 (32 cols each of 384)
__global__ __launch_bounds__(256) void k_mkWc(const void* __restrict__ cw, const void* __restrict__ wih,
                                              const int* __restrict__ flags,
                                              unsigned short* __restrict__ wcH, unsigned short* __restrict__ wcL){
  __shared__ unsigned short sW[128*128];   // [k][j], 32 KB
  __shared__ unsigned short sI[32*136];    // [colLocal][j] padded, 8.5 KB
  const int tid = threadIdx.x;
  const int t = blockIdx.x / 12, tile = blockIdx.x % 12;
  int L=0, s=t;
  if (t>=14){L=4;s=t-14;} else if(t>=12){L=3;s=t-12;} else if(t>=9){L=2;s=t-9;} else if(t>=5){L=1;s=t-5;}
  const int f32 = flags[0];
  const size_t woff = (size_t)(L*5+s)*16384;
  const size_t ioff = (size_t)L*49152 + (size_t)tile*32*128;
  for (int u=tid; u<16384; u+=256) sW[u] = f2bf(LDF(cw, f32, woff + u));
  for (int u=tid; u<4096; u+=256){
    const int r = u>>7, jj = u&127;
    sI[r*136 + jj] = f2bf(LDF(wih, f32, ioff + r*128 + jj));
  }
  __syncthreads();
  const int cl = tid & 31;
  const int kb = (tid>>5)*16;
  for (int k=kb; k<kb+16; ++k){
    float acc = 0.f;
#pragma unroll 4
    for (int j8=0; j8<16; ++j8){
      const short8 a = *(const short8*)(sW + k*128 + j8*8);
      const short8 b = *(const short8*)(sI + cl*136 + j8*8);
#pragma unroll
      for (int q=0;q<8;++q) acc += bf2f((unsigned short)a[q]) * bf2f((unsigned short)b[q]);
    }
    const unsigned short h = f2bf(acc);
    const unsigned short l = f2bf(acc - bf2f(h));
    const size_t oidx = (size_t)t*49152 + (size_t)(tile*32 + cl)*128 + k;
    wcH[oidx] = h; wcL[oidx] = l;
  }
}

// ---------------- xg[dst] = sum ew * x[src] ----------------
// Summation ORDER bit-identical to the r4-frozen body; only load scheduling changed:
// 4 pairs (8 rows) prefetched per main iteration for memory-level parallelism.
__global__ __launch_bounds__(256) void k_agg(const float* __restrict__ m, const int* __restrict__ roff,
                                             const int* __restrict__ es, const float* __restrict__ ewt,
                                             float* __restrict__ agg, const int useW){
  const int node = (blockIdx.x*256 + threadIdx.x) >> 6;
  if (node >= NN) return;
  const int lane = threadIdx.x & 63;
  const int h = lane >> 5, j = lane & 31;
  const int beg = roff[node], end = roff[node+1];
  float ax=0.f, ay=0.f, az=0.f, aw=0.f;
  int e = beg + h;
  // unroll-4: pairs (e,e+2),(e+4,e+6),(e+8,e+10),(e+12,e+14) — loads hoisted, order preserved
  for (; e + 14 < end; e += 16){
    int s_[8]; float w_[8]; float4 v_[8];
#pragma unroll
    for (int q=0;q<8;++q) s_[q] = es[e + q*2];
#pragma unroll
    for (int q=0;q<8;++q) w_[q] = useW ? ewt[e + q*2] : 1.f;
#pragma unroll
    for (int q=0;q<8;++q) v_[q] = *(const float4*)(m + (size_t)s_[q]*CCH + j*4);
#pragma unroll
    for (int p=0;p<4;++p){
      const float w0 = w_[p*2], w1 = w_[p*2+1];
      const float4 v0 = v_[p*2], v1 = v_[p*2+1];
      ax += w0*v0.x + w1*v1.x; ay += w0*v0.y + w1*v1.y;
      az += w0*v0.z + w1*v1.z; aw += w0*v0.w + w1*v1.w;
    }
  }
  for (; e + 2 < end; e += 4){
    const int s0 = es[e], s1 = es[e+2];
    const float w0 = useW ? ewt[e] : 1.f;
    const float w1 = useW ? ewt[e+2] : 1.f;
    const float4 v0 = *(const float4*)(m + (size_t)s0*CCH + j*4);
    const float4 v1 = *(const float4*)(m + (size_t)s1*CCH + j*4);
    ax += w0*v0.x + w1*v1.x; ay += w0*v0.y + w1*v1.y;
    az += w0*v0.z + w1*v1.z; aw += w0*v0.w + w1*v1.w;
  }
  if (e < end){
    const int s0 = es[e];
    const float w0 = useW ? ewt[e] : 1.f;
    const float4 v0 = *(const float4*)(m + (size_t)s0*CCH + j*4);
    ax += w0*v0.x; ay += w0*v0.y; az += w0*v0.z; aw += w0*v0.w;
  }
  ax += __shfl_xor(ax, 32); ay += __shfl_xor(ay, 32);
  az += __shfl_xor(az, 32); aw += __shfl_xor(aw, 32);
  if (h == 0){
    float4 ov; ov.x=ax; ov.y=ay; ov.z=az; ov.w=aw;
    *(float4*)(agg + (size_t)node*CCH + j*4) = ov;
  }
}

// ---------------- fused conv+GRU via MFMA: xf = GRU(xg@Wc, xf) in place ----------------
// r8 EXACT RESTORE (proven 52.8 us): 128 nodes/block, 512 thr (8 waves x 16), grid 313,
// single-buffer staging, 2 barriers/iter. r9 (4 waves) = 73us, r10 (dbuf) = 61us,
// r11 (2-tile) = 104us — time scales with waves/block (latency-bound); do not touch.
__global__ __launch_bounds__(512) void k_gru(const float* __restrict__ xg,
                                             float* __restrict__ xf,
                                             const unsigned short* __restrict__ wcH,  // [384][128]
                                             const unsigned short* __restrict__ wcL,  // [384][128]
                                             const unsigned short* __restrict__ whB,  // [384][128]
                                             const void* __restrict__ bih, const void* __restrict__ bhh,
                                             const size_t boff, const int* __restrict__ flags){
  __shared__ unsigned short s_w[9*16*128];   // 36864 B
  const int tid = threadIdx.x;
  const int wv = tid >> 6;
  const int lane = tid & 63;
  const int quad = lane >> 4;
  const int ln = lane & 15;
  const int m0 = blockIdx.x*128 + wv*16;
  const int f32 = flags[0];
  short8 fah[4], fal[4], fxh[4], fxl[4];
  {
    int arow = m0 + ln; if (arow >= NN) arow = NN-1;
    const float* pa = xg + (size_t)arow*CCH + quad*8;
    const float* px = xf + (size_t)arow*CCH + quad*8;
#pragma unroll
    for (int kk=0;kk<4;++kk){
      split2v(*(const float4*)(pa+kk*32), *(const float4*)(pa+kk*32+4), fah[kk], fal[kk]);
      split2v(*(const float4*)(px+kk*32), *(const float4*)(px+kk*32+4), fxh[kk], fxl[kk]);
    }
  }
#pragma unroll 1
  for (int ct=0; ct<8; ++ct){
    __syncthreads();   // previous iteration's LDS reads complete
    // stage: chunk = mat*3+gate; mat 0=wcH 1=wcL 2=whB; 16 cols x 16 parts each
    for (int u = tid; u < 2304; u += 512){
      const int chunk = u >> 8;
      const int rem = u & 255;
      const int c = rem >> 4, p = rem & 15;
      const int mat = chunk / 3, g = chunk - mat*3;
      const unsigned short* msrc = (mat==0) ? wcH : ((mat==1) ? wcL : whB);
      const unsigned short* src = msrc + ((size_t)(g*CCH + ct*16 + c)*CCH + p*8);
      *(short8*)(s_w + chunk*2048 + c*128 + ((p ^ c)*8)) = *(const short8*)src;
    }
    __syncthreads();
    f32x4 acci[3], acch[3];
#pragma unroll
    for (int g=0;g<3;++g){ acci[g] = (f32x4){0.f,0.f,0.f,0.f}; acch[g] = (f32x4){0.f,0.f,0.f,0.f}; }
#pragma unroll
    for (int kk=0;kk<4;++kk){
      const int sw = ((kk*4+quad) ^ ln)*8;
#pragma unroll
      for (int g=0;g<3;++g){
        const short8 bh_ = *(const short8*)(s_w + g*2048     + ln*128 + sw);
        const short8 bl_ = *(const short8*)(s_w + (3+g)*2048 + ln*128 + sw);
        const short8 bb_ = *(const short8*)(s_w + (6+g)*2048 + ln*128 + sw);
        acci[g] = __builtin_amdgcn_mfma_f32_16x16x32_bf16(fah[kk], bh_, acci[g], 0, 0, 0);
        acci[g] = __builtin_amdgcn_mfma_f32_16x16x32_bf16(fal[kk], bh_, acci[g], 0, 0, 0);
        acci[g] = __builtin_amdgcn_mfma_f32_16x16x32_bf16(fah[kk], bl_, acci[g], 0, 0, 0);
        acch[g] = __builtin_amdgcn_mfma_f32_16x16x32_bf16(fxh[kk], bb_, acch[g], 0, 0, 0);
        acch[g] = __builtin_amdgcn_mfma_f32_16x16x32_bf16(fxl[kk], bb_, acch[g], 0, 0, 0);
      }
    }
    // epilogue for this col-tile
    const int col = ct*16 + ln;
    float bi[3], bh[3];
#pragma unroll
    for (int g=0;g<3;++g){
      bi[g] = LDF(bih, f32, boff + g*CCH + col);
      bh[g] = LDF(bhh, f32, boff + g*CCH + col);
    }
#pragma unroll
    for (int r=0;r<4;++r){
      const int row = m0 + quad*4 + r;
      if (row < NN){
        const size_t idx = (size_t)row*CCH + col;
        const float h = xf[idx];
        const float rr = sigm(acci[0][r] + acch[0][r] + bi[0] + bh[0]);
        const float zz = sigm(acci[1][r] + acch[1][r] + bi[1] + bh[1]);
        const float nv = tanh_f(acci[2][r] + bi[2] + rr*(acch[2][r] + bh[2]));
        xf[idx] = (1.f - zz)*nv + zz*h;
      }
    }
  }
}

// ---------------- GraphNorm ----------------
__global__ __launch_bounds__(256) void k_gn_stats(const float* __restrict__ x, float* __restrict__ accum, const int pre){
  const int tid = threadIdx.x;
  const int ch = tid & 127;
  const int half = tid >> 7;
  const int node0 = blockIdx.x * 128;
  float s = 0.f, s2 = 0.f;
  for (int r = half; r < 128; r += 2){
    const int n = node0 + r;
    if (n >= NN) break;
    float v = x[(size_t)n*CCH + ch];
    if (pre) v = lrelu01(v);
    s += v; s2 += v*v;
  }
  __shared__ float buf[256];
  buf[tid] = s; __syncthreads();
  if (tid < 128) atomicAdd(&accum[ch], buf[tid] + buf[tid+128]);
  __syncthreads();
  buf[tid] = s2; __syncthreads();
  if (tid < 128) atomicAdd(&accum[128+ch], buf[tid] + buf[tid+128]);
}

__global__ void k_gn_final(const float* __restrict__ accum, const void* __restrict__ gw,
                           const void* __restrict__ gb, const void* __restrict__ gms,
                           const size_t off, const int* __restrict__ flags, float* __restrict__ par){
  const int j = threadIdx.x;
  const int f32 = flags[0];
  const float inv = 1.f/(float)NN;
  const float mean = accum[j]*inv;
  const float m2 = accum[128+j]*inv;
  const float ms = LDF(gms, f32, off + j);
  const float var = m2 - 2.f*ms*mean*mean + ms*ms*mean*mean;
  const float sc = LDF(gw, f32, off + j) / sqrtf(var + 1e-5f);
  par[j] = sc;
  par[128+j] = LDF(gb, f32, off + j) - sc*ms*mean;
}

// mode 0: lrelu(a*x+c)   mode 1: a*lrelu(x)+c
__global__ __launch_bounds__(256) void k_gn_apply(float* __restrict__ xf, const float* __restrict__ par, const int mode){
  const int i = blockIdx.x*256 + threadIdx.x;
#pragma unroll
  for (int r=0;r<8;++r){
    const int idx = i + r*640000;
    float v = xf[idx];
    const int ch = idx & 127;
    if (mode == 1) v = lrelu01(v);
    v = par[ch]*v + par[128+ch];
    if (mode == 0) v = lrelu01(v);
    xf[idx] = v;
  }
}

// ---------------- final: lrelu + segment sum (batch sorted -> run-flush atomics) ----------------
__global__ __launch_bounds__(256) void k_final(const float* __restrict__ x, const int* __restrict__ bat,
                                               float* __restrict__ outf){
  const int t = threadIdx.x;
  const int ch = t & 127;
  const int half = t >> 7;
  const int n0 = blockIdx.x*32;
  int cur = -1; float acc = 0.f;
  for (int r = half; r < 32; r += 2){
    const int n = n0 + r;
    const int b = bat[n];
    if (b != cur){
      if (cur >= 0) atomicAdd(&outf[cur*CCH + ch], acc);
      cur = b; acc = 0.f;
    }
    acc += lrelu01(x[(size_t)n*CCH + ch]);
  }
  if (cur >= 0) atomicAdd(&outf[cur*CCH + ch], acc);
}

__global__ __launch_bounds__(256) void k_store(const float* __restrict__ outf, const int* __restrict__ flags, void* __restrict__ out){
  const int i = blockIdx.x*256 + threadIdx.x;
  if (i >= GG*CCH) return;
  if (flags[0]) ((float*)out)[i] = outf[i];
  else ((unsigned short*)out)[i] = f2bf(outf[i]);
}

extern "C" void kernel_launch(void* const* d_in, const int* in_sizes, int n_in,
                              void* d_out, int out_size, void* d_ws, size_t ws_size,
                              hipStream_t stream){
  const void* x_in = d_in[0];
  const void* ew   = d_in[1];
  const void* cw   = d_in[2];
  const void* wih  = d_in[3];
  const void* whh  = d_in[4];
  const void* bih  = d_in[5];
  const void* bhh  = d_in[6];
  const void* gnw  = d_in[7];
  const void* gnb  = d_in[8];
  const void* gnms = d_in[9];
  const void* eidx  = d_in[10];
  const void* batch = d_in[11];

  float* base = (float*)d_ws;
  size_t o = 0;
  float* xf     = base + o; o += (size_t)NN*CCH;   // fp32 state (in-place updated)
  float* xg     = base + o; o += (size_t)NN*CCH;   // gather output
  unsigned short* wcH = (unsigned short*)(base + o); o += 15*384*CCH/2;
  unsigned short* wcL = (unsigned short*)(base + o); o += 15*384*CCH/2;
  unsigned short* whB5= (unsigned short*)(base + o); o += 5*384*CCH/2;
  float* ewt    = base + o; o += EE;
  float* gnpar  = base + o; o += 256;
  int* flags    = (int*)(base + o); o += 2;
  int* bat32    = (int*)(base + o); o += NN;
  int* bsum     = (int*)(base + o); o += 160;
  int* boff2    = (int*)(base + o); o += 160;
  // ---- zero zone (one memset covers outf + gnacc + deg) ----
  float* outf   = base + o; o += GG*CCH;   // 8192
  float* gnacc  = base + o; o += 1024;     // 4 layers x 256
  int* deg      = (int*)(base + o); o += NN;
  // ---- end zero zone ----
  int* roff     = (int*)(base + o); o += NN+1;
  int* pos      = (int*)(base + o); o += NN;
  int* es       = (int*)(base + o); o += EE;

  hipMemsetAsync(outf, 0, (size_t)(GG*CCH + 1024 + NN)*4, stream);

  k_detect<<<1,256,0,stream>>>((const unsigned short*)x_in, (const unsigned int*)eidx, flags);
  k_hist<<<2500,256,0,stream>>>(eidx, flags, deg);
  k_scan1<<<157,256,0,stream>>>(deg, bsum);
  k_scan2<<<1,256,0,stream>>>(bsum, boff2, roff);
  k_scan3<<<157,256,0,stream>>>(deg, boff2, roff, pos);
  k_scatter<<<2500,256,0,stream>>>(eidx, ew, flags, pos, es, ewt);
  k_x2f<<<20000,256,0,stream>>>(x_in, flags, xf);
  k_batcvt<<<157,256,0,stream>>>(batch, flags, bat32);
  for (int L=0; L<5; ++L)
    k_wcvt_bf<<<192,256,0,stream>>>(whh, flags, (size_t)L*384*CCH, whB5 + (size_t)L*384*CCH, 384*CCH);
  k_mkWc<<<180,256,0,stream>>>(cw, wih, flags, wcH, wcL);

  const int steps[5] = {5,4,3,2,1};
  int t = 0;
  for (int L=0; L<5; ++L){
    for (int s=0; s<steps[L]; ++s){
      k_agg<<<10000,256,0,stream>>>(xf, roff, es, ewt, xg, (L<4) ? 1 : 0);
      k_gru<<<313,512,0,stream>>>(xg, xf,
                                  wcH + (size_t)t*384*CCH, wcL + (size_t)t*384*CCH,
                                  whB5 + (size_t)L*384*CCH, bih, bhh, (size_t)L*384, flags);
      t++;
    }
    if (L < 4){
      const int pre = (L==0) ? 0 : 1;
      k_gn_stats<<<313,256,0,stream>>>(xf, gnacc + L*256, pre);
      k_gn_final<<<1,128,0,stream>>>(gnacc + L*256, gnw, gnb, gnms, (size_t)L*CCH, flags, gnpar);
      k_gn_apply<<<2500,256,0,stream>>>(xf, gnpar, pre);
    }
  }
  k_final<<<1250,256,0,stream>>>(xf, bat32, outf);
  k_store<<<32,256,0,stream>>>(outf, flags, d_out);
}

// Round 13
// 1715.169 us; speedup vs baseline: 1.4658x; 1.0074x over previous
//
#include <hip/hip_runtime.h>
#include <hip/hip_bf16.h>

#define NN 40000
#define EE 640000
#define CCH 128
#define GG 64

typedef __attribute__((ext_vector_type(8))) short short8;
typedef __attribute__((ext_vector_type(4))) float f32x4;

__device__ __forceinline__ float lrelu01(float v){ return v > 0.f ? v : 0.01f*v; }
__device__ __forceinline__ float sigm(float v){ return 1.f/(1.f + __expf(-v)); }
__device__ __forceinline__ float tanh_f(float v){
  v = fminf(fmaxf(v, -15.f), 15.f);
  const float t = __expf(2.f*v);
  return (t - 1.f)/(t + 1.f);
}
__device__ __forceinline__ unsigned short f2bf(float f){
  union { float f; unsigned int u; } v; v.f = f;
  const unsigned int r = v.u + 0x7FFFu + ((v.u >> 16) & 1u);
  return (unsigned short)(r >> 16);
}
__device__ __forceinline__ float bf2f(unsigned short h){
  union { unsigned int u; float f; } v; v.u = ((unsigned int)h) << 16;
  return v.f;
}
// 2-term split: x = hi + lo (~2^-17 rel err; error floor is agg ordering, r4/r5 evidence)
__device__ __forceinline__ void split2v(const float4 a, const float4 b, short8& hi, short8& lo){
  const float v[8] = {a.x,a.y,a.z,a.w,b.x,b.y,b.z,b.w};
#pragma unroll
  for (int i=0;i<8;++i){
    const unsigned short h = f2bf(v[i]);
    hi[i] = (short)h;
    lo[i] = (short)f2bf(v[i] - bf2f(h));
  }
}
// dual-dtype loads: flags[0]=floats are f32, flags[1]=ints are i64
__device__ __forceinline__ float LDF(const void* p, int f32, size_t i){
  return f32 ? ((const float*)p)[i] : bf2f(((const unsigned short*)p)[i]);
}
__device__ __forceinline__ int LDI(const void* p, int i64, size_t i){
  return i64 ? (int)((const long long*)p)[i] : ((const int*)p)[i];
}

// ---------------- dtype detection (device-side, graph-safe) ----------------
__global__ __launch_bounds__(256) void k_detect(const unsigned short* __restrict__ xh,
                                                const unsigned int* __restrict__ ei,
                                                int* __restrict__ flags){
  __shared__ int s1[256], s2[256];
  const int t = threadIdx.x;
  int c1 = 0, c2 = 0;
  for (int i=0;i<8;++i){
    const unsigned short w = xh[t*8 + i];
    const int e = (w >> 7) & 0xFF;
    if (e < 100 || e > 140) c1++;
    const unsigned int o = ei[(t*8 + i)*2 + 1];
    if (o) c2++;
  }
  s1[t]=c1; s2[t]=c2; __syncthreads();
  for (int off=128; off; off>>=1){ if (t<off){ s1[t]+=s1[t+off]; s2[t]+=s2[t+off]; } __syncthreads(); }
  if (t==0){
    flags[0] = (s1[0] > 64) ? 1 : 0;
    flags[1] = (s2[0] < 16) ? 1 : 0;
  }
}

// ---------------- CSR build ----------------
__global__ __launch_bounds__(256) void k_hist(const void* __restrict__ eidx, const int* __restrict__ flags,
                                              int* __restrict__ deg){
  const int e = blockIdx.x*256 + threadIdx.x;
  if (e >= EE) return;
  atomicAdd(&deg[LDI(eidx, flags[1], (size_t)EE + e)], 1);
}

__global__ __launch_bounds__(256) void k_scan1(const int* __restrict__ deg, int* __restrict__ bsum){
  __shared__ int s[256];
  const int t = threadIdx.x;
  const int i = blockIdx.x*256 + t;
  s[t] = (i < NN) ? deg[i] : 0;
  __syncthreads();
  for (int off=128; off; off>>=1){ if (t<off) s[t]+=s[t+off]; __syncthreads(); }
  if (t==0) bsum[blockIdx.x] = s[0];
}

__global__ __launch_bounds__(256) void k_scan2(const int* __restrict__ bsum, int* __restrict__ boff,
                                               int* __restrict__ roff){
  __shared__ int s[256];
  const int t = threadIdx.x;
  const int v = (t < 157) ? bsum[t] : 0;
  s[t] = v; __syncthreads();
  for (int off=1; off<256; off<<=1){
    const int u = (t>=off) ? s[t-off] : 0;
    __syncthreads(); s[t] += u; __syncthreads();
  }
  if (t < 157) boff[t] = s[t] - v;   // exclusive
  if (t == 0) roff[NN] = EE;
}

__global__ __launch_bounds__(256) void k_scan3(const int* __restrict__ deg, const int* __restrict__ boff,
                                               int* __restrict__ roff, int* __restrict__ pos){
  __shared__ int s[256];
  const int t = threadIdx.x;
  const int i = blockIdx.x*256 + t;
  const int v = (i < NN) ? deg[i] : 0;
  s[t] = v; __syncthreads();
  for (int off=1; off<256; off<<=1){
    const int u = (t>=off) ? s[t-off] : 0;
    __syncthreads(); s[t] += u; __syncthreads();
  }
  if (i < NN){
    const int ex = boff[blockIdx.x] + s[t] - v;
    roff[i] = ex; pos[i] = ex;
  }
}

__global__ __launch_bounds__(256) void k_scatter(const void* __restrict__ eidx, const void* __restrict__ ew,
                                                 const int* __restrict__ flags,
                                                 int* __restrict__ pos, int* __restrict__ es, float* __restrict__ ewt){
  const int e = blockIdx.x*256 + threadIdx.x;
  if (e >= EE) return;
  const int i64 = flags[1];
  const int d = LDI(eidx, i64, (size_t)EE + e);
  const int p = atomicAdd(&pos[d], 1);
  es[p] = LDI(eidx, i64, e);
  ewt[p] = LDF(ew, flags[0], e);
}

// ---------------- converts (x2f + batcvt merged) ----------------
__global__ __launch_bounds__(256) void k_x2f(const void* __restrict__ xin, const int* __restrict__ flags,
                                             float* __restrict__ xf,
                                             const void* __restrict__ batch, int* __restrict__ bat32){
  const int i = blockIdx.x*256 + threadIdx.x;
  if (i < NN*CCH) xf[i] = LDF(xin, flags[0], i);
  if (i < NN) bat32[i] = LDI(batch, flags[1], i);
}

__global__ __launch_bounds__(256) void k_wcvt_bf(const void* __restrict__ w, const int* __restrict__ flags,
                                                 unsigned short* __restrict__ o, const int n){
  const int i = blockIdx.x*256 + threadIdx.x;
  if (i < n) o[i] = f2bf(LDF(w, flags[0], i));
}

// ---------------- Wc[t] = convW[t] @ wih[L(t)]^T, stored Bt-layout [t][col][k], hi/lo split ----
// grid 180: t = bx/12 (15 steps), tile = bx%12 (32 cols each of 384)
__global__ __launch_bounds__(256) void k_mkWc(const void* __restrict__ cw, const void* __restrict__ wih,
                                              const int* __restrict__ flags,
                                              unsigned short* __restrict__ wcH, unsigned short* __restrict__ wcL){
  __shared__ unsigned short sW[128*128];   // [k][j], 32 KB
  __shared__ unsigned short sI[32*136];    // [colLocal][j] padded, 8.5 KB
  const int tid = threadIdx.x;
  const int t = blockIdx.x / 12, tile = blockIdx.x % 12;
  int L=0, s=t;
  if (t>=14){L=4;s=t-14;} else if(t>=12){L=3;s=t-12;} else if(t>=9){L=2;s=t-9;} else if(t>=5){L=1;s=t-5;}
  const int f32 = flags[0];
  const size_t woff = (size_t)(L*5+s)*16384;
  const size_t ioff = (size_t)L*49152 + (size_t)tile*32*128;
  for (int u=tid; u<16384; u+=256) sW[u] = f2bf(LDF(cw, f32, woff + u));
  for (int u=tid; u<4096; u+=256){
    const int r = u>>7, jj = u&127;
    sI[r*136 + jj] = f2bf(LDF(wih, f32, ioff + r*128 + jj));
  }
  __syncthreads();
  const int cl = tid & 31;
  const int kb = (tid>>5)*16;
  for (int k=kb; k<kb+16; ++k){
    float acc = 0.f;
#pragma unroll 4
    for (int j8=0; j8<16; ++j8){
      const short8 a = *(const short8*)(sW + k*128 + j8*8);
      const short8 b = *(const short8*)(sI + cl*136 + j8*8);
#pragma unroll
      for (int q=0;q<8;++q) acc += bf2f((unsigned short)a[q]) * bf2f((unsigned short)b[q]);
    }
    const unsigned short h = f2bf(acc);
    const unsigned short l = f2bf(acc - bf2f(h));
    const size_t oidx = (size_t)t*49152 + (size_t)(tile*32 + cl)*128 + k;
    wcH[oidx] = h; wcL[oidx] = l;
  }
}

// ---------------- xg[dst] = sum ew * x[src]  (roofline-frozen; order fixed since r4) ----------------
__global__ __launch_bounds__(256) void k_agg(const float* __restrict__ m, const int* __restrict__ roff,
                                             const int* __restrict__ es, const float* __restrict__ ewt,
                                             float* __restrict__ agg, const int useW){
  const int node = (blockIdx.x*256 + threadIdx.x) >> 6;
  if (node >= NN) return;
  const int lane = threadIdx.x & 63;
  const int h = lane >> 5, j = lane & 31;
  const int beg = roff[node], end = roff[node+1];
  float ax=0.f, ay=0.f, az=0.f, aw=0.f;
  int e = beg + h;
  for (; e + 14 < end; e += 16){
    int s_[8]; float w_[8]; float4 v_[8];
#pragma unroll
    for (int q=0;q<8;++q) s_[q] = es[e + q*2];
#pragma unroll
    for (int q=0;q<8;++q) w_[q] = useW ? ewt[e + q*2] : 1.f;
#pragma unroll
    for (int q=0;q<8;++q) v_[q] = *(const float4*)(m + (size_t)s_[q]*CCH + j*4);
#pragma unroll
    for (int p=0;p<4;++p){
      const float w0 = w_[p*2], w1 = w_[p*2+1];
      const float4 v0 = v_[p*2], v1 = v_[p*2+1];
      ax += w0*v0.x + w1*v1.x; ay += w0*v0.y + w1*v1.y;
      az += w0*v0.z + w1*v1.z; aw += w0*v0.w + w1*v1.w;
    }
  }
  for (; e + 2 < end; e += 4){
    const int s0 = es[e], s1 = es[e+2];
    const float w0 = useW ? ewt[e] : 1.f;
    const float w1 = useW ? ewt[e+2] : 1.f;
    const float4 v0 = *(const float4*)(m + (size_t)s0*CCH + j*4);
    const float4 v1 = *(const float4*)(m + (size_t)s1*CCH + j*4);
    ax += w0*v0.x + w1*v1.x; ay += w0*v0.y + w1*v1.y;
    az += w0*v0.z + w1*v1.z; aw += w0*v0.w + w1*v1.w;
  }
  if (e < end){
    const int s0 = es[e];
    const float w0 = useW ? ewt[e] : 1.f;
    const float4 v0 = *(const float4*)(m + (size_t)s0*CCH + j*4);
    ax += w0*v0.x; ay += w0*v0.y; az += w0*v0.z; aw += w0*v0.w;
  }
  ax += __shfl_xor(ax, 32); ay += __shfl_xor(ay, 32);
  az += __shfl_xor(az, 32); aw += __shfl_xor(aw, 32);
  if (h == 0){
    float4 ov; ov.x=ax; ov.y=ay; ov.z=az; ov.w=aw;
    *(float4*)(agg + (size_t)node*CCH + j*4) = ov;
  }
}

// ---------------- fused conv+GRU via MFMA: xf = GRU(xg@Wc, xf) in place ----------------
// r8 structure (128 nodes/block, 512 thr, grid 313) with 32-col staging: 4 iterations x 73.7 KB,
// 8 barriers total (was 16). Same waves/block, same total staged bytes, same per-element MFMA
// order -> absmax identical. r9 (fewer waves) / r10 (dbuf regs) / r11 (2-tile) all regressed;
// barrier count is the one untried axis.
__global__ __launch_bounds__(512) void k_gru(const float* __restrict__ xg,
                                             float* __restrict__ xf,
                                             const unsigned short* __restrict__ wcH,  // [384][128]
                                             const unsigned short* __restrict__ wcL,  // [384][128]
                                             const unsigned short* __restrict__ whB,  // [384][128]
                                             const void* __restrict__ bih, const void* __restrict__ bhh,
                                             const size_t boff, const int* __restrict__ flags){
  __shared__ unsigned short s_w[9*32*128];   // 73728 B
  const int tid = threadIdx.x;
  const int wv = tid >> 6;
  const int lane = tid & 63;
  const int quad = lane >> 4;
  const int ln = lane & 15;
  const int m0 = blockIdx.x*128 + wv*16;
  const int f32 = flags[0];
  short8 fah[4], fal[4], fxh[4], fxl[4];
  {
    int arow = m0 + ln; if (arow >= NN) arow = NN-1;
    const float* pa = xg + (size_t)arow*CCH + quad*8;
    const float* px = xf + (size_t)arow*CCH + quad*8;
#pragma unroll
    for (int kk=0;kk<4;++kk){
      split2v(*(const float4*)(pa+kk*32), *(const float4*)(pa+kk*32+4), fah[kk], fal[kk]);
      split2v(*(const float4*)(px+kk*32), *(const float4*)(px+kk*32+4), fxh[kk], fxl[kk]);
    }
  }
#pragma unroll 1
  for (int ct=0; ct<4; ++ct){
    __syncthreads();   // previous iteration's LDS reads complete
    // stage: chunk = mat*3+gate; mat 0=wcH 1=wcL 2=whB; 32 cols x 16 parts each
    for (int u = tid; u < 4608; u += 512){
      const int chunk = u >> 9;
      const int rem = u & 511;
      const int c = rem >> 4, p = rem & 15;
      const int mat = chunk / 3, g = chunk - mat*3;
      const unsigned short* msrc = (mat==0) ? wcH : ((mat==1) ? wcL : whB);
      const unsigned short* src = msrc + ((size_t)(g*CCH + ct*32 + c)*CCH + p*8);
      *(short8*)(s_w + chunk*4096 + c*128 + ((p ^ (c & 15))*8)) = *(const short8*)src;
    }
    __syncthreads();
#pragma unroll 1
    for (int hf=0; hf<2; ++hf){
      const int cl = hf*16 + ln;
      f32x4 acci[3], acch[3];
#pragma unroll
      for (int g=0;g<3;++g){ acci[g] = (f32x4){0.f,0.f,0.f,0.f}; acch[g] = (f32x4){0.f,0.f,0.f,0.f}; }
#pragma unroll
      for (int kk=0;kk<4;++kk){
        const int sw = ((kk*4+quad) ^ ln)*8;
#pragma unroll
        for (int g=0;g<3;++g){
          const short8 bh_ = *(const short8*)(s_w + g*4096     + cl*128 + sw);
          const short8 bl_ = *(const short8*)(s_w + (3+g)*4096 + cl*128 + sw);
          const short8 bb_ = *(const short8*)(s_w + (6+g)*4096 + cl*128 + sw);
          acci[g] = __builtin_amdgcn_mfma_f32_16x16x32_bf16(fah[kk], bh_, acci[g], 0, 0, 0);
          acci[g] = __builtin_amdgcn_mfma_f32_16x16x32_bf16(fal[kk], bh_, acci[g], 0, 0, 0);
          acci[g] = __builtin_amdgcn_mfma_f32_16x16x32_bf16(fah[kk], bl_, acci[g], 0, 0, 0);
          acch[g] = __builtin_amdgcn_mfma_f32_16x16x32_bf16(fxh[kk], bb_, acch[g], 0, 0, 0);
          acch[g] = __builtin_amdgcn_mfma_f32_16x16x32_bf16(fxl[kk], bb_, acch[g], 0, 0, 0);
        }
      }
      // epilogue for this col-tile
      const int col = ct*32 + cl;
      float bi[3], bh[3];
#pragma unroll
      for (int g=0;g<3;++g){
        bi[g] = LDF(bih, f32, boff + g*CCH + col);
        bh[g] = LDF(bhh, f32, boff + g*CCH + col);
      }
#pragma unroll
      for (int r=0;r<4;++r){
        const int row = m0 + quad*4 + r;
        if (row < NN){
          const size_t idx = (size_t)row*CCH + col;
          const float h = xf[idx];
          const float rr = sigm(acci[0][r] + acch[0][r] + bi[0] + bh[0]);
          const float zz = sigm(acci[1][r] + acch[1][r] + bi[1] + bh[1]);
          const float nv = tanh_f(acci[2][r] + bi[2] + rr*(acch[2][r] + bh[2]));
          xf[idx] = (1.f - zz)*nv + zz*h;
        }
      }
    }
  }
}

// ---------------- GraphNorm ----------------
__global__ __launch_bounds__(256) void k_gn_stats(const float* __restrict__ x, float* __restrict__ accum, const int pre){
  const int tid = threadIdx.x;
  const int ch = tid & 127;
  const int half = tid >> 7;
  const int node0 = blockIdx.x * 128;
  float s = 0.f, s2 = 0.f;
  for (int r = half; r < 128; r += 2){
    const int n = node0 + r;
    if (n >= NN) break;
    float v = x[(size_t)n*CCH + ch];
    if (pre) v = lrelu01(v);
    s += v; s2 += v*v;
  }
  __shared__ float buf[256];
  buf[tid] = s; __syncthreads();
  if (tid < 128) atomicAdd(&accum[ch], buf[tid] + buf[tid+128]);
  __syncthreads();
  buf[tid] = s2; __syncthreads();
  if (tid < 128) atomicAdd(&accum[128+ch], buf[tid] + buf[tid+128]);
}

// mode 0: lrelu(a*x+c)   mode 1: a*lrelu(x)+c — gn_final fused (bit-identical expressions)
__global__ __launch_bounds__(256) void k_gn_apply(float* __restrict__ xf, const float* __restrict__ accum,
                                                  const void* __restrict__ gw, const void* __restrict__ gb,
                                                  const void* __restrict__ gms, const size_t off,
                                                  const int* __restrict__ flags, const int mode){
  const int i = blockIdx.x*256 + threadIdx.x;
  const int ch = i & 127;     // 640000 % 128 == 0 -> channel constant across r
  const int f32 = flags[0];
  const float inv = 1.f/(float)NN;
  const float mean = accum[ch]*inv;
  const float m2 = accum[128+ch]*inv;
  const float ms = LDF(gms, f32, off + ch);
  const float var = m2 - 2.f*ms*mean*mean + ms*ms*mean*mean;
  const float sc = LDF(gw, f32, off + ch) / sqrtf(var + 1e-5f);
  const float sh = LDF(gb, f32, off + ch) - sc*ms*mean;
#pragma unroll
  for (int r=0;r<8;++r){
    const int idx = i + r*640000;
    float v = xf[idx];
    if (mode == 1) v = lrelu01(v);
    v = sc*v + sh;
    if (mode == 0) v = lrelu01(v);
    xf[idx] = v;
  }
}

// ---------------- final: lrelu + segment sum (batch sorted -> run-flush atomics) ----------------
__global__ __launch_bounds__(256) void k_final(const float* __restrict__ x, const int* __restrict__ bat,
                                               float* __restrict__ outf){
  const int t = threadIdx.x;
  const int ch = t & 127;
  const int half = t >> 7;
  const int n0 = blockIdx.x*32;
  int cur = -1; float acc = 0.f;
  for (int r = half; r < 32; r += 2){
    const int n = n0 + r;
    const int b = bat[n];
    if (b != cur){
      if (cur >= 0) atomicAdd(&outf[cur*CCH + ch], acc);
      cur = b; acc = 0.f;
    }
    acc += lrelu01(x[(size_t)n*CCH + ch]);
  }
  if (cur >= 0) atomicAdd(&outf[cur*CCH + ch], acc);
}

__global__ __launch_bounds__(256) void k_store(const float* __restrict__ outf, const int* __restrict__ flags, void* __restrict__ out){
  const int i = blockIdx.x*256 + threadIdx.x;
  if (i >= GG*CCH) return;
  if (flags[0]) ((float*)out)[i] = outf[i];
  else ((unsigned short*)out)[i] = f2bf(outf[i]);
}

extern "C" void kernel_launch(void* const* d_in, const int* in_sizes, int n_in,
                              void* d_out, int out_size, void* d_ws, size_t ws_size,
                              hipStream_t stream){
  const void* x_in = d_in[0];
  const void* ew   = d_in[1];
  const void* cw   = d_in[2];
  const void* wih  = d_in[3];
  const void* whh  = d_in[4];
  const void* bih  = d_in[5];
  const void* bhh  = d_in[6];
  const void* gnw  = d_in[7];
  const void* gnb  = d_in[8];
  const void* gnms = d_in[9];
  const void* eidx  = d_in[10];
  const void* batch = d_in[11];

  float* base = (float*)d_ws;
  size_t o = 0;
  float* xf     = base + o; o += (size_t)NN*CCH;   // fp32 state (in-place updated)
  float* xg     = base + o; o += (size_t)NN*CCH;   // gather output
  unsigned short* wcH = (unsigned short*)(base + o); o += 15*384*CCH/2;
  unsigned short* wcL = (unsigned short*)(base + o); o += 15*384*CCH/2;
  unsigned short* whB5= (unsigned short*)(base + o); o += 5*384*CCH/2;
  float* ewt    = base + o; o += EE;
  int* flags    = (int*)(base + o); o += 2;
  int* bat32    = (int*)(base + o); o += NN;
  int* bsum     = (int*)(base + o); o += 160;
  int* boff2    = (int*)(base + o); o += 160;
  // ---- zero zone (one memset covers outf + gnacc + deg) ----
  float* outf   = base + o; o += GG*CCH;   // 8192
  float* gnacc  = base + o; o += 1024;     // 4 layers x 256
  int* deg      = (int*)(base + o); o += NN;
  // ---- end zero zone ----
  int* roff     = (int*)(base + o); o += NN+1;
  int* pos      = (int*)(base + o); o += NN;
  int* es       = (int*)(base + o); o += EE;

  hipMemsetAsync(outf, 0, (size_t)(GG*CCH + 1024 + NN)*4, stream);

  k_detect<<<1,256,0,stream>>>((const unsigned short*)x_in, (const unsigned int*)eidx, flags);
  k_hist<<<2500,256,0,stream>>>(eidx, flags, deg);
  k_scan1<<<157,256,0,stream>>>(deg, bsum);
  k_scan2<<<1,256,0,stream>>>(bsum, boff2, roff);
  k_scan3<<<157,256,0,stream>>>(deg, boff2, roff, pos);
  k_scatter<<<2500,256,0,stream>>>(eidx, ew, flags, pos, es, ewt);
  k_x2f<<<20000,256,0,stream>>>(x_in, flags, xf, batch, bat32);
  k_wcvt_bf<<<960,256,0,stream>>>(whh, flags, whB5, 5*384*CCH);
  k_mkWc<<<180,256,0,stream>>>(cw, wih, flags, wcH, wcL);

  const int steps[5] = {5,4,3,2,1};
  int t = 0;
  for (int L=0; L<5; ++L){
    for (int s=0; s<steps[L]; ++s){
      k_agg<<<10000,256,0,stream>>>(xf, roff, es, ewt, xg, (L<4) ? 1 : 0);
      k_gru<<<313,512,0,stream>>>(xg, xf,
                                  wcH + (size_t)t*384*CCH, wcL + (size_t)t*384*CCH,
                                  whB5 + (size_t)L*384*CCH, bih, bhh, (size_t)L*384, flags);
      t++;
    }
    if (L < 4){
      const int pre = (L==0) ? 0 : 1;
      k_gn_stats<<<313,256,0,stream>>>(xf, gnacc + L*256, pre);
      k_gn_apply<<<2500,256,0,stream>>>(xf, gnacc + L*256, gnw, gnb, gnms, (size_t)L*CCH, flags, pre);
    }
  }
  k_final<<<1250,256,0,stream>>>(xf, bat32, outf);
  k_store<<<32,256,0,stream>>>(outf, flags, d_out);
}